// Round 11
// baseline (201.620 us; speedup 1.0000x reference)
//
#include <hip/hip_runtime.h>
#include <hip/hip_bf16.h>

#define SPIX 1000
#define NCLS 21
#define PP (512*512)          // pixels per image, 2^18
#define NB_IMG 8
#define EPB (NCLS*PP)

// scatter geometry: 4096-pixel window per block; claims computed once per
// window (phase A), replayed for all 21 chunks (phase B).
#define WIN 4096
#define WPB (PP/WIN)              // 64 windows per image
#define NBLK (WPB*NB_IMG)         // 512 scatter blocks
#define DUMP 1000                 // garbage accumulator slot (rows sized 1024)

// ws layout (floats)
#define R_OFF   0                      // [8][21][1000]
#define TR_OFF  (NB_IMG*NCLS*SPIX)     // [8]
#define NS_OFF  (TR_OFF + NB_IMG)      // [1] norm^2
#define CNT_OFF (NS_OFF + 1)           // [1] valid count
#define CTR_OFF (CNT_OFF + 1)          // [1] trace completion counter
#define WS_FLOATS (CTR_OFF + 1)
#define RP_OFF  ((WS_FLOATS + 3) & ~3) // partials, 16B-aligned
#define RP_FLOATS ((size_t)NBLK * NCLS * SPIX)   // 10.75M floats = 43 MB

__device__ __forceinline__ void fatomic_add(float* p, float v) {
    unsafeAtomicAdd(p, v);   // native ds_add_f32 / global_atomic_add_f32
}

__global__ __launch_bounds__(512, 4) void scatter_kernel(const float* __restrict__ pred,
                                                         const int* __restrict__ seg,
                                                         const float* __restrict__ W,
                                                         float* __restrict__ Rout,
                                                         float* __restrict__ Rp,
                                                         int use_part,
                                                         float* __restrict__ ns,
                                                         float* __restrict__ cnt) {
    if (blockIdx.y == NB_IMG) {            // -------- scalars blocks (x<64) --------
        if (blockIdx.x < 48) {
            const float4* W4 = (const float4*)W;
            const int n4 = (NB_IMG * SPIX * SPIX) / 4;
            float s = 0.f;
            for (int i = blockIdx.x * 512 + threadIdx.x; i < n4; i += 48 * 512) {
                float4 v = W4[i];
                s += v.x*v.x + v.y*v.y + v.z*v.z + v.w*v.w;
            }
            #pragma unroll
            for (int off = 32; off; off >>= 1) s += __shfl_xor(s, off);
            if ((threadIdx.x & 63) == 0) fatomic_add(ns, s);
        } else {
            const int4* s4 = (const int4*)seg;
            const int n4 = (NB_IMG * PP) / 4;
            int c = 0;
            for (int i = (blockIdx.x - 48) * 512 + threadIdx.x; i < n4; i += 16 * 512) {
                int4 v = s4[i];
                c += ((unsigned)v.x < SPIX) + ((unsigned)v.y < SPIX) + ((unsigned)v.z < SPIX) + ((unsigned)v.w < SPIX);
            }
            float f = (float)c;
            #pragma unroll
            for (int off = 32; off; off >>= 1) f += __shfl_xor(f, off);
            if ((threadIdx.x & 63) == 0) fatomic_add(cnt, f);
        }
        return;
    }
    // -------- scatter blocks --------
    __shared__ float         Rw[8][1024];   // wave-private accumulators, 32 KB
    __shared__ unsigned char Mk[8][1024];   // wave-private claim markers, 8 KB
    const int b    = blockIdx.y;
    const int wb   = blockIdx.x;            // window 0..63
    const int tid  = threadIdx.x;
    const int wave = tid >> 6;
    const unsigned char lane = (unsigned char)(tid & 63);
    const unsigned p0 = (unsigned)wb * WIN;

    for (int i = tid; i < 8 * 1024; i += 512) ((float*)Rw)[i] = 0.f;

    volatile float*         vR = Rw[wave];
    volatile unsigned char* vM = Mk[wave];
    float* aR = (float*)Rw[wave];

    const float* pb   = pred + (size_t)b * EPB;
    const int*   segb = seg + (size_t)b * PP + p0;

    // ---- phase A: claims once per window (2 stripes x 4 elems/lane) ----
    unsigned sA[8];
    unsigned m_w1 = 0, m_w2 = 0, m_fb = 0, firsts = 0;
    #pragma unroll
    for (int st = 0; st < 2; ++st) {
        int4 sv = *(const int4*)(segb + st * 2048 + tid * 4);
        unsigned s0 = ((unsigned)sv.x < SPIX) ? (unsigned)sv.x : DUMP;
        unsigned s1 = ((unsigned)sv.y < SPIX) ? (unsigned)sv.y : DUMP;
        unsigned s2 = ((unsigned)sv.z < SPIX) ? (unsigned)sv.z : DUMP;
        unsigned s3 = ((unsigned)sv.w < SPIX) ? (unsigned)sv.w : DUMP;
        // dedup pattern: first equal index per slot (transitive-safe)
        unsigned f1 = (s1 == s0) ? 0u : 1u;
        unsigned f2 = (s2 == s0) ? 0u : ((s2 == s1) ? 1u : 2u);
        unsigned f3 = (s3 == s0) ? 0u : ((s3 == s1) ? 1u : ((s3 == s2) ? 2u : 3u));
        firsts |= (f1 | (f2 << 2) | (f3 << 4)) << (st * 8);
        if (f1 != 1u) s1 = DUMP;
        if (f2 != 2u) s2 = DUMP;
        if (f3 != 3u) s3 = DUMP;
        sA[st*4+0] = s0; sA[st*4+1] = s1; sA[st*4+2] = s2; sA[st*4+3] = s3;
        // round 1
        #pragma unroll
        for (int k = 0; k < 4; ++k) vM[sA[st*4+k]] = lane;
        unsigned char rd[4];
        #pragma unroll
        for (int k = 0; k < 4; ++k) rd[k] = vM[sA[st*4+k]];
        // round 2 (losers re-claim; winners claim garbage slot 1008)
        unsigned a2[4];
        #pragma unroll
        for (int k = 0; k < 4; ++k) a2[k] = (rd[k] == lane) ? 1008u : sA[st*4+k];
        #pragma unroll
        for (int k = 0; k < 4; ++k) vM[a2[k]] = lane;
        unsigned char rd2[4];
        #pragma unroll
        for (int k = 0; k < 4; ++k) rd2[k] = vM[a2[k]];
        #pragma unroll
        for (int k = 0; k < 4; ++k) {
            bool w1 = (rd[k] == lane);
            bool w2 = (rd2[k] == lane) && !w1;
            bool fb = !w1 && !w2 && (sA[st*4+k] != DUMP);
            m_w1 |= (w1 ? 1u : 0u) << (st*4+k);
            m_w2 |= (w2 ? 1u : 0u) << (st*4+k);
            m_fb |= (fb ? 1u : 0u) << (st*4+k);
        }
    }
    __syncthreads();   // Rw zero-init complete

    // ---- phase B: replay per chunk c ----
    const bool mtid = (tid < 250);
    #pragma unroll 1
    for (int c = 0; c < NCLS; ++c) {
        #pragma unroll
        for (int st = 0; st < 2; ++st) {
            unsigned fk = (unsigned)c * PP + p0 + (unsigned)(st * 2048 + tid * 4);
            unsigned sp = fk / 21u;
            unsigned ch = fk - sp * 21u;
            float vA[4];
            #pragma unroll
            for (int k = 0; k < 4; ++k) {
                vA[k] = pb[(ch << 18) + sp];
                ch++;
                bool cc = (ch == 21u);
                sp += cc ? 1u : 0u;
                ch  = cc ? 0u : ch;
            }
            // dup-merge replay (branchless)
            unsigned fst = firsts >> (st * 8);
            unsigned f1 = fst & 3u, f2 = (fst >> 2) & 3u, f3 = (fst >> 4) & 3u;
            vA[0] += (f1 == 0u) ? vA[1] : 0.f;
            vA[0] += (f2 == 0u) ? vA[2] : 0.f;
            vA[1] += (f2 == 1u) ? vA[2] : 0.f;
            vA[0] += (f3 == 0u) ? vA[3] : 0.f;
            vA[1] += (f3 == 1u) ? vA[3] : 0.f;
            vA[2] += (f3 == 2u) ? vA[3] : 0.f;
            unsigned mw1 = m_w1 >> (st*4), mw2 = m_w2 >> (st*4), mfb = m_fb >> (st*4);
            // w1 RMW
            float od[4];
            #pragma unroll
            for (int k = 0; k < 4; ++k) od[k] = vR[sA[st*4+k]];
            #pragma unroll
            for (int k = 0; k < 4; ++k)
                vR[((mw1 >> k) & 1u) ? sA[st*4+k] : (1016u + k)] = od[k] + vA[k];
            // w2 RMW (reads see w1 writes via in-order DS FIFO)
            float od2[4];
            #pragma unroll
            for (int k = 0; k < 4; ++k) od2[k] = vR[sA[st*4+k]];
            #pragma unroll
            for (int k = 0; k < 4; ++k)
                vR[((mw2 >> k) & 1u) ? sA[st*4+k] : (1016u + k)] = od2[k] + vA[k];
            asm volatile("" ::: "memory");
            // fallback (~1%): double-losers on the atomic pipe
            #pragma unroll
            for (int k = 0; k < 4; ++k)
                if ((mfb >> k) & 1u) fatomic_add(&aR[sA[st*4+k]], vA[k]);
        }
        __syncthreads();
        if (mtid) {   // merge 8 copies (f4), emit partial, re-zero
            float4 a = make_float4(0.f, 0.f, 0.f, 0.f);
            #pragma unroll
            for (int w = 0; w < 8; ++w) {
                float4 t = ((const float4*)Rw[w])[tid];
                a.x += t.x; a.y += t.y; a.z += t.z; a.w += t.w;
                ((float4*)Rw[w])[tid] = make_float4(0.f, 0.f, 0.f, 0.f);
            }
            if (use_part) {
                ((float4*)(Rp + ((size_t)(b * WPB + wb) * NCLS + c) * SPIX))[tid] = a;
            } else {
                float* dst = Rout + ((size_t)b * NCLS + c) * SPIX + tid * 4;
                fatomic_add(dst + 0, a.x);
                fatomic_add(dst + 1, a.y);
                fatomic_add(dst + 2, a.z);
                fatomic_add(dst + 3, a.w);
            }
        }
        __syncthreads();
    }
}

// sum the 64 window-partials per (b,c)
__global__ __launch_bounds__(256) void reduce_kernel(const float* __restrict__ Rp,
                                                     float* __restrict__ Rout) {
    const int c = blockIdx.x, b = blockIdx.y, tid = threadIdx.x;
    if (tid < 250) {
        float4 a = make_float4(0.f, 0.f, 0.f, 0.f);
        #pragma unroll 4
        for (int w = 0; w < WPB; ++w) {
            float4 t = ((const float4*)(Rp + ((size_t)(b * WPB + w) * NCLS + c) * SPIX))[tid];
            a.x += t.x; a.y += t.y; a.z += t.z; a.w += t.w;
        }
        ((float4*)(Rout + ((size_t)b * NCLS + c) * SPIX))[tid] = a;
    }
}

// trace[b] = sum_{s,t} L[b,s,t] * sum_c R[b,c,s]*R[b,c,t]; last block finalizes.
__global__ __launch_bounds__(512) void trace_kernel(const float* __restrict__ L,
                                                    const float* __restrict__ R,
                                                    float* __restrict__ traces,
                                                    const float* __restrict__ ns,
                                                    const float* __restrict__ cnt,
                                                    unsigned* __restrict__ ctr,
                                                    float* __restrict__ out) {
    __shared__ float Rl[NCLS * SPIX];   // 84 KB
    const int b = blockIdx.y;
    const float* Rb = R + (size_t)b * NCLS * SPIX;
    for (int i = threadIdx.x; i < NCLS * SPIX; i += 512) Rl[i] = Rb[i];
    __syncthreads();

    const int wave = threadIdx.x >> 6;
    const int lane = threadIdx.x & 63;
    const float* Lb = L + (size_t)b * SPIX * SPIX;

    const int s0 = (blockIdx.x * 8 + wave) * 4;
    bool val[4];
    const float4* Lr[4];
    #pragma unroll
    for (int r = 0; r < 4; ++r) {
        int sr = s0 + r;
        val[r] = sr < SPIX;
        Lr[r] = (const float4*)(Lb + (size_t)(val[r] ? sr : (SPIX - 1)) * SPIX);
    }

    float acc[4][NCLS];
    #pragma unroll
    for (int r = 0; r < 4; ++r)
        #pragma unroll
        for (int c = 0; c < NCLS; ++c) acc[r][c] = 0.f;

    #pragma unroll
    for (int it = 0; it < 4; ++it) {
        int idx = it * 64 + lane;
        if (idx < SPIX / 4) {
            float4 l[4];
            #pragma unroll
            for (int r = 0; r < 4; ++r)
                l[r] = val[r] ? Lr[r][idx] : make_float4(0.f, 0.f, 0.f, 0.f);
            #pragma unroll
            for (int c = 0; c < NCLS; ++c) {
                float4 rr = *(const float4*)&Rl[c * SPIX + idx * 4];
                #pragma unroll
                for (int r = 0; r < 4; ++r)
                    acc[r][c] += l[r].x * rr.x + l[r].y * rr.y + l[r].z * rr.z + l[r].w * rr.w;
            }
        }
    }

    float partial = 0.f;
    #pragma unroll
    for (int c = 0; c < NCLS; ++c)
        #pragma unroll
        for (int r = 0; r < 4; ++r)
            if (val[r]) partial += Rl[c * SPIX + s0 + r] * acc[r][c];

    #pragma unroll
    for (int off = 32; off; off >>= 1) partial += __shfl_xor(partial, off);
    if (lane == 0) fatomic_add(&traces[b], partial);

    __syncthreads();
    if (threadIdx.x == 0) {
        __threadfence();
        unsigned old = atomicAdd(ctr, 1u);
        if (old == 32u * NB_IMG - 1u) {
            __threadfence();
            float t = 0.f;
            #pragma unroll
            for (int i = 0; i < NB_IMG; ++i)
                t += __hip_atomic_load(&traces[i], __ATOMIC_RELAXED, __HIP_MEMORY_SCOPE_AGENT);
            float denom = cnt[0] + 1e-16f;
            out[0] = (2.f / sqrtf(ns[0])) * t / (denom * denom) / (float)NB_IMG;
        }
    }
}

extern "C" void kernel_launch(void* const* d_in, const int* in_sizes, int n_in,
                              void* d_out, int out_size, void* d_ws, size_t ws_size,
                              hipStream_t stream) {
    const float* pred = (const float*)d_in[0];
    const float* Wc   = (const float*)d_in[1];
    const float* Lc   = (const float*)d_in[2];
    const int*   seg  = (const int*)d_in[3];
    float* ws = (float*)d_ws;
    float* out = (float*)d_out;

    const size_t need = ((size_t)RP_OFF + RP_FLOATS) * sizeof(float);
    const int use_part = (ws_size >= need) ? 1 : 0;

    hipMemsetAsync(d_ws, 0, WS_FLOATS * sizeof(float), stream);

    scatter_kernel<<<dim3(WPB, NB_IMG + 1), 512, 0, stream>>>(
        pred, seg, Wc, ws + R_OFF, ws + RP_OFF, use_part, ws + NS_OFF, ws + CNT_OFF);

    if (use_part)
        reduce_kernel<<<dim3(NCLS, NB_IMG), 256, 0, stream>>>(ws + RP_OFF, ws + R_OFF);

    trace_kernel<<<dim3(32, NB_IMG), 512, 0, stream>>>(
        Lc, ws + R_OFF, ws + TR_OFF, ws + NS_OFF, ws + CNT_OFF,
        (unsigned*)(ws + CTR_OFF), out);
}

// Round 12
// 141.595 us; speedup vs baseline: 1.4239x; 1.4239x over previous
//
#include <hip/hip_runtime.h>
#include <hip/hip_bf16.h>

#define SPIX 1000
#define NCLS 21
#define PP (512*512)          // pixels per image, 2^18
#define NB_IMG 8
#define EPB (NCLS*PP)         // elements per batch in pred (= 21*2^18 f-values)

// scatter geometry: contiguous 32768-wide f-window per block; 2^15 | 2^18 so
// the class row c = f>>18 is CONSTANT within a block.
#define FWIN 32768
#define BLKS_PER_B (EPB / FWIN)   // 168
#define DUMP 1000                 // garbage accumulator slot (rows sized 1024)

// ws layout (floats)
#define R_OFF   0                      // [8][21][1000]
#define TR_OFF  (NB_IMG*NCLS*SPIX)     // [8]
#define NS_OFF  (TR_OFF + NB_IMG)      // [1] norm^2
#define CNT_OFF (NS_OFF + 1)           // [1] valid count
#define CTR_OFF (CNT_OFF + 1)          // [1] trace-block completion counter
#define WS_FLOATS (CTR_OFF + 1)

__device__ __forceinline__ void fatomic_add(float* p, float v) {
    unsafeAtomicAdd(p, v);   // native ds_add_f32 / global_atomic_add_f32
}

#define CLOBBER() asm volatile("" ::: "memory")

// Scatter + (on blockIdx.y==8) the ||W||^2 and valid-count reductions.
// R10 protocol; ordering via per-PHASE memory clobbers instead of per-op
// volatile (volatile DS accesses get a conservative lgkmcnt(0) drain EACH —
// ~400 stall cyc/iter; clobbers keep program order + kill store-forwarding
// while letting the backend batch waits).
__global__ __launch_bounds__(512, 8) void scatter_kernel(const float* __restrict__ pred,
                                                         const int* __restrict__ seg,
                                                         const float* __restrict__ W,
                                                         float* __restrict__ Rout,
                                                         float* __restrict__ ns,
                                                         float* __restrict__ cnt) {
    if (blockIdx.y == NB_IMG) {            // -------- scalars blocks --------
        if (blockIdx.x < 128) {
            const float4* W4 = (const float4*)W;
            const int n4 = (NB_IMG * SPIX * SPIX) / 4;
            float s = 0.f;
            for (int i = blockIdx.x * 512 + threadIdx.x; i < n4; i += 128 * 512) {
                float4 v = W4[i];
                s += v.x*v.x + v.y*v.y + v.z*v.z + v.w*v.w;
            }
            #pragma unroll
            for (int off = 32; off; off >>= 1) s += __shfl_xor(s, off);
            if ((threadIdx.x & 63) == 0) fatomic_add(ns, s);
        } else {
            const int4* s4 = (const int4*)seg;
            const int n4 = (NB_IMG * PP) / 4;
            int c = 0;
            for (int i = (blockIdx.x - 128) * 512 + threadIdx.x; i < n4; i += 40 * 512) {
                int4 v = s4[i];
                c += ((unsigned)v.x < SPIX) + ((unsigned)v.y < SPIX) + ((unsigned)v.z < SPIX) + ((unsigned)v.w < SPIX);
            }
            float f = (float)c;
            #pragma unroll
            for (int off = 32; off; off >>= 1) f += __shfl_xor(f, off);
            if ((threadIdx.x & 63) == 0) fatomic_add(cnt, f);
        }
        return;
    }
    // -------- scatter blocks --------
    __shared__ float          Rw[8][1024];   // wave-private accumulators, 32 KB
    __shared__ unsigned short Mk[8][1024];   // wave-private claim markers, 16 KB
    const int b    = blockIdx.y;
    const int tid  = threadIdx.x;
    const int wave = tid >> 6;
    const unsigned short lane = (unsigned short)(tid & 63);
    const unsigned f0 = (unsigned)blockIdx.x * FWIN;
    const unsigned c0 = f0 >> 18;            // constant class row for this block
    const unsigned p0 = f0 & (PP - 1);       // window start pixel (never wraps)

    for (int i = tid; i < 8 * 1024; i += 512) ((float*)Rw)[i] = 0.f;
    __syncthreads();

    float*          wR = Rw[wave];
    unsigned short* wM = Mk[wave];

    const float* pb   = pred + (size_t)b * EPB;
    const int*   segb = seg + (size_t)b * PP + p0;

    // issue-next-iteration loads (seg int4 + 4 pred gathers)
#define PREF(E0, SV, VV) do {                                     \
        SV = *(const int4*)(segb + (E0));                         \
        unsigned fk = f0 + (unsigned)(E0);                        \
        unsigned sp = fk / 21u;                                   \
        unsigned ch = fk - sp * 21u;                              \
        _Pragma("unroll")                                         \
        for (int k = 0; k < 4; ++k) {                             \
            VV[k] = pb[(ch << 18) + sp];                          \
            ch++;                                                 \
            bool c21 = (ch == 21u);                               \
            sp += c21 ? 1u : 0u;                                  \
            ch  = c21 ? 0u : ch;                                  \
        }                                                         \
    } while (0)

    int4 svN; float vN[4];
    PREF(tid * 4, svN, vN);                                  // prologue: it=0

    for (int it = 0; it < FWIN / (512 * 4); ++it) {          // 16 iterations
        int4 sv = svN;
        float vA[4] = {vN[0], vN[1], vN[2], vN[3]};
        if (it + 1 < FWIN / (512 * 4)) {
            PREF(((it + 1) * 512 + tid) * 4, svN, vN);       // in flight during protocol
        }
        int sA[4];
        #pragma unroll
        for (int k = 0; k < 4; ++k) {
            int s = (&sv.x)[k];
            sA[k] = ((unsigned)s < SPIX) ? s : DUMP;
        }
        // lane-local dedup: merge equal bins so a lane wins a bin at most once
        #pragma unroll
        for (int i = 0; i < 3; ++i)
            #pragma unroll
            for (int j = i + 1; j < 4; ++j) {
                bool e = (sA[j] == sA[i]) && (sA[i] != DUMP);
                vA[i] += e ? vA[j] : 0.f;
                sA[j]  = e ? DUMP  : sA[j];
            }
        // phase 1: claims (4 ds_write_b16, batched waits)
        #pragma unroll
        for (int k = 0; k < 4; ++k) wM[sA[k]] = lane;
        CLOBBER();
        // phase 2: claim readback (4 ds_read_u16)
        unsigned short rd[4];
        #pragma unroll
        for (int k = 0; k < 4; ++k) rd[k] = wM[sA[k]];
        CLOBBER();
        // phase 3: RMW reads (unconditional; losers read harmlessly)
        float od[4];
        #pragma unroll
        for (int k = 0; k < 4; ++k) od[k] = wR[sA[k]];
        CLOBBER();
        // phase 4: winner writes, branchless (losers write garbage to DUMP)
        bool lose1[4];
        #pragma unroll
        for (int k = 0; k < 4; ++k) {
            lose1[k] = (rd[k] != lane);
            wR[lose1[k] ? DUMP : sA[k]] = od[k] + vA[k];
        }
        CLOBBER();   // order winner writes before fallbacks (DS FIFO does in HW)
        // phase 5: loser fallback on the atomic pipe (~13% of lanes)
        #pragma unroll
        for (int k = 0; k < 4; ++k) {
            if (lose1[k]) fatomic_add(&wR[sA[k]], vA[k]);
        }
    }
#undef PREF
    __syncthreads();

    // merge 8 wave copies, one global atomic per bin
    float* Rb = Rout + (size_t)b * NCLS * SPIX + (size_t)c0 * SPIX;
    for (int i = tid; i < SPIX; i += 512) {
        float a = 0.f;
        #pragma unroll
        for (int w = 0; w < 8; ++w) a += Rw[w][i];
        fatomic_add(&Rb[i], a);
    }
}

// trace[b] = sum_{s,t} L[b,s,t] * sum_c R[b,c,s]*R[b,c,t]; last block finalizes.
__global__ __launch_bounds__(512) void trace_kernel(const float* __restrict__ L,
                                                    const float* __restrict__ R,
                                                    float* __restrict__ traces,
                                                    const float* __restrict__ ns,
                                                    const float* __restrict__ cnt,
                                                    unsigned* __restrict__ ctr,
                                                    float* __restrict__ out) {
    __shared__ float Rl[NCLS * SPIX];   // 84 KB
    const int b = blockIdx.y;
    const float* Rb = R + (size_t)b * NCLS * SPIX;
    for (int i = threadIdx.x; i < NCLS * SPIX; i += 512) Rl[i] = Rb[i];
    __syncthreads();

    const int wave = threadIdx.x >> 6;
    const int lane = threadIdx.x & 63;
    const float* Lb = L + (size_t)b * SPIX * SPIX;

    const int s0 = (blockIdx.x * 8 + wave) * 4;   // 32 blocks * 8 waves * 4 rows = 1024
    bool val[4];
    const float4* Lr[4];
    #pragma unroll
    for (int r = 0; r < 4; ++r) {
        int sr = s0 + r;
        val[r] = sr < SPIX;
        Lr[r] = (const float4*)(Lb + (size_t)(val[r] ? sr : (SPIX - 1)) * SPIX);
    }

    float acc[4][NCLS];
    #pragma unroll
    for (int r = 0; r < 4; ++r)
        #pragma unroll
        for (int c = 0; c < NCLS; ++c) acc[r][c] = 0.f;

    #pragma unroll
    for (int it = 0; it < 4; ++it) {
        int idx = it * 64 + lane;          // float4 index within row, 0..249
        if (idx < SPIX / 4) {
            float4 l[4];
            #pragma unroll
            for (int r = 0; r < 4; ++r)
                l[r] = val[r] ? Lr[r][idx] : make_float4(0.f, 0.f, 0.f, 0.f);
            #pragma unroll
            for (int c = 0; c < NCLS; ++c) {
                float4 rr = *(const float4*)&Rl[c * SPIX + idx * 4];
                #pragma unroll
                for (int r = 0; r < 4; ++r)
                    acc[r][c] += l[r].x * rr.x + l[r].y * rr.y + l[r].z * rr.z + l[r].w * rr.w;
            }
        }
    }

    float partial = 0.f;
    #pragma unroll
    for (int c = 0; c < NCLS; ++c)
        #pragma unroll
        for (int r = 0; r < 4; ++r)
            if (val[r]) partial += Rl[c * SPIX + s0 + r] * acc[r][c];

    #pragma unroll
    for (int off = 32; off; off >>= 1) partial += __shfl_xor(partial, off);
    if (lane == 0) fatomic_add(&traces[b], partial);

    __syncthreads();
    if (threadIdx.x == 0) {
        __threadfence();
        unsigned old = atomicAdd(ctr, 1u);
        if (old == 32u * NB_IMG - 1u) {    // last block finalizes
            __threadfence();
            float t = 0.f;
            #pragma unroll
            for (int i = 0; i < NB_IMG; ++i)
                t += __hip_atomic_load(&traces[i], __ATOMIC_RELAXED, __HIP_MEMORY_SCOPE_AGENT);
            float denom = cnt[0] + 1e-16f;
            out[0] = (2.f / sqrtf(ns[0])) * t / (denom * denom) / (float)NB_IMG;
        }
    }
}

extern "C" void kernel_launch(void* const* d_in, const int* in_sizes, int n_in,
                              void* d_out, int out_size, void* d_ws, size_t ws_size,
                              hipStream_t stream) {
    const float* pred = (const float*)d_in[0];
    const float* Wc   = (const float*)d_in[1];
    const float* Lc   = (const float*)d_in[2];
    const int*   seg  = (const int*)d_in[3];
    float* ws = (float*)d_ws;
    float* out = (float*)d_out;

    hipMemsetAsync(d_ws, 0, WS_FLOATS * sizeof(float), stream);

    scatter_kernel<<<dim3(BLKS_PER_B, NB_IMG + 1), 512, 0, stream>>>(
        pred, seg, Wc, ws + R_OFF, ws + NS_OFF, ws + CNT_OFF);

    trace_kernel<<<dim3(32, NB_IMG), 512, 0, stream>>>(
        Lc, ws + R_OFF, ws + TR_OFF, ws + NS_OFF, ws + CNT_OFF,
        (unsigned*)(ws + CTR_OFF), out);
}

// Round 13
// 139.164 us; speedup vs baseline: 1.4488x; 1.0175x over previous
//
#include <hip/hip_runtime.h>
#include <hip/hip_bf16.h>

#define SPIX 1000
#define NCLS 21
#define PP (512*512)          // pixels per image, 2^18
#define NB_IMG 8
#define EPB (NCLS*PP)         // elements per batch in pred (= 21*2^18 f-values)

// scatter geometry: contiguous 32768-wide f-window per block; 2^15 | 2^18 so
// the class row c = f>>18 is CONSTANT within a block.
#define FWIN 32768
#define BLKS_PER_B (EPB / FWIN)   // 168
#define DUMP 1000                 // garbage accumulator slot (rows sized 1024)

// ws layout (floats)
#define R_OFF   0                      // [8][21][1000]
#define TR_OFF  (NB_IMG*NCLS*SPIX)     // [8]
#define NS_OFF  (TR_OFF + NB_IMG)      // [1] norm^2
#define CNT_OFF (NS_OFF + 1)           // [1] valid count
#define CTR_OFF (CNT_OFF + 1)          // [1] trace-block completion counter
#define WS_FLOATS (CTR_OFF + 1)

__device__ __forceinline__ void fatomic_add(float* p, float v) {
    unsafeAtomicAdd(p, v);   // native ds_add_f32 / global_atomic_add_f32
}

#define CLOBBER() asm volatile("" ::: "memory")

// Scatter + (on blockIdx.y==8) the ||W||^2 and valid-count reductions.
// R12 protocol (per-phase clobbers, batched lgkm waits) with u8 markers:
// LDS 40 KB -> exactly 4 blocks/CU (32 waves) to close the wave-overlap gap
// to the DS-pipe floor (~280 cyc/wave-iter of banked+conflict+atomic work).
__global__ __launch_bounds__(512, 8) void scatter_kernel(const float* __restrict__ pred,
                                                         const int* __restrict__ seg,
                                                         const float* __restrict__ W,
                                                         float* __restrict__ Rout,
                                                         float* __restrict__ ns,
                                                         float* __restrict__ cnt) {
    if (blockIdx.y == NB_IMG) {            // -------- scalars blocks --------
        if (blockIdx.x < 128) {
            const float4* W4 = (const float4*)W;
            const int n4 = (NB_IMG * SPIX * SPIX) / 4;
            float s = 0.f;
            for (int i = blockIdx.x * 512 + threadIdx.x; i < n4; i += 128 * 512) {
                float4 v = W4[i];
                s += v.x*v.x + v.y*v.y + v.z*v.z + v.w*v.w;
            }
            #pragma unroll
            for (int off = 32; off; off >>= 1) s += __shfl_xor(s, off);
            if ((threadIdx.x & 63) == 0) fatomic_add(ns, s);
        } else {
            const int4* s4 = (const int4*)seg;
            const int n4 = (NB_IMG * PP) / 4;
            int c = 0;
            for (int i = (blockIdx.x - 128) * 512 + threadIdx.x; i < n4; i += 40 * 512) {
                int4 v = s4[i];
                c += ((unsigned)v.x < SPIX) + ((unsigned)v.y < SPIX) + ((unsigned)v.z < SPIX) + ((unsigned)v.w < SPIX);
            }
            float f = (float)c;
            #pragma unroll
            for (int off = 32; off; off >>= 1) f += __shfl_xor(f, off);
            if ((threadIdx.x & 63) == 0) fatomic_add(cnt, f);
        }
        return;
    }
    // -------- scatter blocks --------
    __shared__ float         Rw[8][1024];   // wave-private accumulators, 32 KB
    __shared__ unsigned char Mk[8][1024];   // wave-private claim markers, 8 KB
    const int b    = blockIdx.y;
    const int tid  = threadIdx.x;
    const int wave = tid >> 6;
    const unsigned char lane = (unsigned char)(tid & 63);
    const unsigned f0 = (unsigned)blockIdx.x * FWIN;
    const unsigned c0 = f0 >> 18;            // constant class row for this block
    const unsigned p0 = f0 & (PP - 1);       // window start pixel (never wraps)

    for (int i = tid; i < 8 * 1024; i += 512) ((float*)Rw)[i] = 0.f;
    __syncthreads();

    float*         wR = Rw[wave];
    unsigned char* wM = Mk[wave];

    const float* pb   = pred + (size_t)b * EPB;
    const int*   segb = seg + (size_t)b * PP + p0;

    // issue-next-iteration loads (seg int4 + 4 pred gathers)
#define PREF(E0, SV, VV) do {                                     \
        SV = *(const int4*)(segb + (E0));                         \
        unsigned fk = f0 + (unsigned)(E0);                        \
        unsigned sp = fk / 21u;                                   \
        unsigned ch = fk - sp * 21u;                              \
        _Pragma("unroll")                                         \
        for (int k = 0; k < 4; ++k) {                             \
            VV[k] = pb[(ch << 18) + sp];                          \
            ch++;                                                 \
            bool c21 = (ch == 21u);                               \
            sp += c21 ? 1u : 0u;                                  \
            ch  = c21 ? 0u : ch;                                  \
        }                                                         \
    } while (0)

    int4 svN; float vN[4];
    PREF(tid * 4, svN, vN);                                  // prologue: it=0

    for (int it = 0; it < FWIN / (512 * 4); ++it) {          // 16 iterations
        int4 sv = svN;
        float vA[4] = {vN[0], vN[1], vN[2], vN[3]};
        if (it + 1 < FWIN / (512 * 4)) {
            PREF(((it + 1) * 512 + tid) * 4, svN, vN);       // in flight during protocol
        }
        int sA[4];
        #pragma unroll
        for (int k = 0; k < 4; ++k) {
            int s = (&sv.x)[k];
            sA[k] = ((unsigned)s < SPIX) ? s : DUMP;
        }
        // lane-local dedup: merge equal bins so a lane wins a bin at most once
        #pragma unroll
        for (int i = 0; i < 3; ++i)
            #pragma unroll
            for (int j = i + 1; j < 4; ++j) {
                bool e = (sA[j] == sA[i]) && (sA[i] != DUMP);
                vA[i] += e ? vA[j] : 0.f;
                sA[j]  = e ? DUMP  : sA[j];
            }
        // phase 1: claims (4 ds_write_b8, batched waits)
        #pragma unroll
        for (int k = 0; k < 4; ++k) wM[sA[k]] = lane;
        CLOBBER();
        // phase 2: claim readback (4 ds_read_u8)
        unsigned char rd[4];
        #pragma unroll
        for (int k = 0; k < 4; ++k) rd[k] = wM[sA[k]];
        CLOBBER();
        // phase 3: RMW reads (unconditional; losers read harmlessly)
        float od[4];
        #pragma unroll
        for (int k = 0; k < 4; ++k) od[k] = wR[sA[k]];
        CLOBBER();
        // phase 4: winner writes, branchless (losers write garbage to DUMP)
        bool lose1[4];
        #pragma unroll
        for (int k = 0; k < 4; ++k) {
            lose1[k] = (rd[k] != lane);
            wR[lose1[k] ? DUMP : sA[k]] = od[k] + vA[k];
        }
        CLOBBER();   // order winner writes before fallbacks (DS FIFO does in HW)
        // phase 5: loser fallback on the atomic pipe (~12% of lanes)
        #pragma unroll
        for (int k = 0; k < 4; ++k) {
            if (lose1[k]) fatomic_add(&wR[sA[k]], vA[k]);
        }
    }
#undef PREF
    __syncthreads();

    // merge 8 wave copies, one global atomic per bin
    float* Rb = Rout + (size_t)b * NCLS * SPIX + (size_t)c0 * SPIX;
    for (int i = tid; i < SPIX; i += 512) {
        float a = 0.f;
        #pragma unroll
        for (int w = 0; w < 8; ++w) a += Rw[w][i];
        fatomic_add(&Rb[i], a);
    }
}

// trace[b] = sum_{s,t} L[b,s,t] * sum_c R[b,c,s]*R[b,c,t]; last block finalizes.
__global__ __launch_bounds__(512) void trace_kernel(const float* __restrict__ L,
                                                    const float* __restrict__ R,
                                                    float* __restrict__ traces,
                                                    const float* __restrict__ ns,
                                                    const float* __restrict__ cnt,
                                                    unsigned* __restrict__ ctr,
                                                    float* __restrict__ out) {
    __shared__ float Rl[NCLS * SPIX];   // 84 KB
    const int b = blockIdx.y;
    const float* Rb = R + (size_t)b * NCLS * SPIX;
    for (int i = threadIdx.x; i < NCLS * SPIX; i += 512) Rl[i] = Rb[i];
    __syncthreads();

    const int wave = threadIdx.x >> 6;
    const int lane = threadIdx.x & 63;
    const float* Lb = L + (size_t)b * SPIX * SPIX;

    const int s0 = (blockIdx.x * 8 + wave) * 4;   // 32 blocks * 8 waves * 4 rows = 1024
    bool val[4];
    const float4* Lr[4];
    #pragma unroll
    for (int r = 0; r < 4; ++r) {
        int sr = s0 + r;
        val[r] = sr < SPIX;
        Lr[r] = (const float4*)(Lb + (size_t)(val[r] ? sr : (SPIX - 1)) * SPIX);
    }

    float acc[4][NCLS];
    #pragma unroll
    for (int r = 0; r < 4; ++r)
        #pragma unroll
        for (int c = 0; c < NCLS; ++c) acc[r][c] = 0.f;

    #pragma unroll
    for (int it = 0; it < 4; ++it) {
        int idx = it * 64 + lane;          // float4 index within row, 0..249
        if (idx < SPIX / 4) {
            float4 l[4];
            #pragma unroll
            for (int r = 0; r < 4; ++r)
                l[r] = val[r] ? Lr[r][idx] : make_float4(0.f, 0.f, 0.f, 0.f);
            #pragma unroll
            for (int c = 0; c < NCLS; ++c) {
                float4 rr = *(const float4*)&Rl[c * SPIX + idx * 4];
                #pragma unroll
                for (int r = 0; r < 4; ++r)
                    acc[r][c] += l[r].x * rr.x + l[r].y * rr.y + l[r].z * rr.z + l[r].w * rr.w;
            }
        }
    }

    float partial = 0.f;
    #pragma unroll
    for (int c = 0; c < NCLS; ++c)
        #pragma unroll
        for (int r = 0; r < 4; ++r)
            if (val[r]) partial += Rl[c * SPIX + s0 + r] * acc[r][c];

    #pragma unroll
    for (int off = 32; off; off >>= 1) partial += __shfl_xor(partial, off);
    if (lane == 0) fatomic_add(&traces[b], partial);

    __syncthreads();
    if (threadIdx.x == 0) {
        __threadfence();
        unsigned old = atomicAdd(ctr, 1u);
        if (old == 32u * NB_IMG - 1u) {    // last block finalizes
            __threadfence();
            float t = 0.f;
            #pragma unroll
            for (int i = 0; i < NB_IMG; ++i)
                t += __hip_atomic_load(&traces[i], __ATOMIC_RELAXED, __HIP_MEMORY_SCOPE_AGENT);
            float denom = cnt[0] + 1e-16f;
            out[0] = (2.f / sqrtf(ns[0])) * t / (denom * denom) / (float)NB_IMG;
        }
    }
}

extern "C" void kernel_launch(void* const* d_in, const int* in_sizes, int n_in,
                              void* d_out, int out_size, void* d_ws, size_t ws_size,
                              hipStream_t stream) {
    const float* pred = (const float*)d_in[0];
    const float* Wc   = (const float*)d_in[1];
    const float* Lc   = (const float*)d_in[2];
    const int*   seg  = (const int*)d_in[3];
    float* ws = (float*)d_ws;
    float* out = (float*)d_out;

    hipMemsetAsync(d_ws, 0, WS_FLOATS * sizeof(float), stream);

    scatter_kernel<<<dim3(BLKS_PER_B, NB_IMG + 1), 512, 0, stream>>>(
        pred, seg, Wc, ws + R_OFF, ws + NS_OFF, ws + CNT_OFF);

    trace_kernel<<<dim3(32, NB_IMG), 512, 0, stream>>>(
        Lc, ws + R_OFF, ws + TR_OFF, ws + NS_OFF, ws + CNT_OFF,
        (unsigned*)(ws + CTR_OFF), out);
}